// Round 2
// 1135.349 us; speedup vs baseline: 1.0983x; 1.0983x over previous
//
#include <hip/hip_runtime.h>

// Equivariant linear: per-irrep block-diagonal matmul.
// Irreps: 256x0e + 128x1o + 64x2e + 32x3o, B = 131072, FEAT = 1184.
// y[b,v,i] = (1/sqrt(mul)) * sum_u w[v,u] * x[b,u,i]
//
// v2.1: identical structure to v2 (coalesced float4 loads -> bf16 LDS
// transpose tile xseg[m][u], double-buffered with T14 issue-early /
// write-late split; MFMA fragments via ds_read_b128; swapped operands
// for D>1 so stores are runs of D contiguous floats; register-persistent
// weights). Hardening: __align__(16) on the LDS buffer for the
// bf16x8/bf16x4 vector accesses.

typedef __attribute__((ext_vector_type(8))) __bf16 bf16x8;
typedef __attribute__((ext_vector_type(4))) __bf16 bf16x4;
typedef __attribute__((ext_vector_type(4))) float f32x4;

constexpr int FEAT = 1184;

template<int MUL, int D, int XO, int WO, int BT, int MINW>
__global__ __launch_bounds__(256, MINW)
void eqlin(const float* __restrict__ x, const float* __restrict__ w,
           float* __restrict__ out, int n_tiles, float cnorm)
{
    constexpr int KS   = MUL / 32;          // K-steps of 32
    constexpr int SEG  = MUL * D;           // floats per row in this block
    constexpr int VT   = MUL / 16;          // v-tiles (N dim)
    constexpr int VTW  = (VT >= 4) ? VT / 4 : 1;   // v-tiles per wave
    constexpr int MT   = BT * D / 16;       // m-tiles (GEMM M dim / 16)
    constexpr int MSP  = (VT >= 4) ? 1 : 4 / VT;   // waves splitting M
    constexpr int MTW  = MT / MSP;          // m-tiles per wave
    constexpr int Kp   = MUL + 8;           // padded LDS row (bf16, x8 aligned)
    constexpr int BUFE = BT * D * Kp;       // elems per LDS buffer
    constexpr int NLD  = BT * SEG / 1024;   // float4 loads / thread / tile

    __shared__ __align__(16) __bf16 smem[2 * BUFE];

    const int tid  = threadIdx.x;
    const int lane = tid & 63;
    const int wid  = tid >> 6;
    const int l16  = lane & 15;
    const int quad = lane >> 4;

    const int vt0 = (VT >= 4) ? wid * VTW : (wid & (VT - 1));
    const int mt0 = (VT >= 4) ? 0 : (wid / VT) * MTW;

    // ---- weight fragments (persistent in registers) ----
    // lane: v-row = l16, u = quad*8 + j. Same register image serves as the
    // B-operand (D==1) or the A-operand (D>1).
    bf16x8 wfrag[VTW][KS];
#pragma unroll
    for (int vt = 0; vt < VTW; ++vt) {
        const float* wp = w + WO + (long)((vt0 + vt) * 16 + l16) * MUL;
#pragma unroll
        for (int ks = 0; ks < KS; ++ks) {
            const float4 q0 = *(const float4*)(wp + ks * 32 + quad * 8);
            const float4 q1 = *(const float4*)(wp + ks * 32 + quad * 8 + 4);
            wfrag[vt][ks][0] = (__bf16)(q0.x * cnorm);
            wfrag[vt][ks][1] = (__bf16)(q0.y * cnorm);
            wfrag[vt][ks][2] = (__bf16)(q0.z * cnorm);
            wfrag[vt][ks][3] = (__bf16)(q0.w * cnorm);
            wfrag[vt][ks][4] = (__bf16)(q1.x * cnorm);
            wfrag[vt][ks][5] = (__bf16)(q1.y * cnorm);
            wfrag[vt][ks][6] = (__bf16)(q1.z * cnorm);
            wfrag[vt][ks][7] = (__bf16)(q1.w * cnorm);
        }
    }

    // ---- loop-invariant staging geometry ----
    // element e = (c*256 + tid)*4 ; bl = e/SEG ; fo = e%SEG = u*D + i
    int xoff[NLD];
#pragma unroll
    for (int c = 0; c < NLD; ++c) {
        const int e  = (c * 256 + tid) * 4;
        const int bl = e / SEG;
        xoff[c] = bl * FEAT + XO + (e - bl * SEG);
    }

    float4 pf[NLD];

    auto stage_load = [&](int tt) {
        const float* xb = x + (long)tt * BT * FEAT;
#pragma unroll
        for (int c = 0; c < NLD; ++c)
            pf[c] = *(const float4*)(xb + xoff[c]);
    };

    auto stage_write = [&](int hb) {
        __bf16* dst = smem + hb * BUFE;
#pragma unroll
        for (int c = 0; c < NLD; ++c) {
            const int e  = (c * 256 + tid) * 4;
            const int bl = e / SEG;
            const int fo = e - bl * SEG;
            if constexpr (D == 1) {
                bf16x4 v4;
                v4[0] = (__bf16)pf[c].x; v4[1] = (__bf16)pf[c].y;
                v4[2] = (__bf16)pf[c].z; v4[3] = (__bf16)pf[c].w;
                *(bf16x4*)(dst + bl * Kp + fo) = v4;   // ds_write_b64
            } else {
                const float fv[4] = {pf[c].x, pf[c].y, pf[c].z, pf[c].w};
#pragma unroll
                for (int j = 0; j < 4; ++j) {
                    const int f = fo + j;
                    const int u = f / D;
                    const int i = f - u * D;
                    dst[(bl * D + i) * Kp + u] = (__bf16)fv[j];
                }
            }
        }
    };

    const int G = gridDim.x;
    int t = blockIdx.x;

    if (t < n_tiles) { stage_load(t); stage_write(0); }
    __syncthreads();

    int buf = 0;
    for (; t < n_tiles; t += G) {
        const int tn = t + G;
        if (tn < n_tiles) stage_load(tn);      // issue early (T14)

        // ---- compute from smem[buf] ----
        const __bf16* src = smem + buf * BUFE;
        f32x4 acc[VTW][MTW];
#pragma unroll
        for (int vt = 0; vt < VTW; ++vt)
#pragma unroll
            for (int mt = 0; mt < MTW; ++mt)
                acc[vt][mt] = f32x4{0.f, 0.f, 0.f, 0.f};

#pragma unroll
        for (int mt = 0; mt < MTW; ++mt) {
            const int m = (mt0 + mt) * 16 + l16;
            bf16x8 xf[KS];
#pragma unroll
            for (int ks = 0; ks < KS; ++ks)
                xf[ks] = *(const bf16x8*)(src + m * Kp + ks * 32 + quad * 8);
#pragma unroll
            for (int ks = 0; ks < KS; ++ks)
#pragma unroll
                for (int vt = 0; vt < VTW; ++vt) {
                    if constexpr (D == 1)
                        acc[vt][mt] = __builtin_amdgcn_mfma_f32_16x16x32_bf16(
                            xf[ks], wfrag[vt][ks], acc[vt][mt], 0, 0, 0);
                    else   // swap operands: D[row=v][col=m]
                        acc[vt][mt] = __builtin_amdgcn_mfma_f32_16x16x32_bf16(
                            wfrag[vt][ks], xf[ks], acc[vt][mt], 0, 0, 0);
                }
        }

        // ---- stores ----
        {
            const long rb = (long)t * BT;
#pragma unroll
            for (int vt = 0; vt < VTW; ++vt)
#pragma unroll
                for (int mt = 0; mt < MTW; ++mt) {
                    if constexpr (D == 1) {
                        // D[row=m][col=v]: 16-lane contiguous stores
                        const int v = (vt0 + vt) * 16 + l16;
#pragma unroll
                        for (int r = 0; r < 4; ++r) {
                            const long b = rb + (mt0 + mt) * 16 + quad * 4 + r;
                            out[b * FEAT + XO + v] = acc[vt][mt][r];
                        }
                    } else {
                        // D[row=v][col=m]: lanes run along m -> runs of D
                        const int m  = (mt0 + mt) * 16 + l16;
                        const int bl = m / D;
                        const int i  = m - bl * D;
#pragma unroll
                        for (int r = 0; r < 4; ++r) {
                            const int v = (vt0 + vt) * 16 + quad * 4 + r;
                            out[(rb + bl) * FEAT + XO + v * D + i] =
                                acc[vt][mt][r];
                        }
                    }
                }
        }

        if (tn < n_tiles) stage_write(buf ^ 1);  // vmcnt wait + cvt + ds_write
        __syncthreads();
        buf ^= 1;
    }
}

extern "C" void kernel_launch(void* const* d_in, const int* in_sizes, int n_in,
                              void* d_out, int out_size, void* d_ws, size_t ws_size,
                              hipStream_t stream) {
    const float* x = (const float*)d_in[0];
    const float* w = (const float*)d_in[1];
    float* out = (float*)d_out;

    // block 0: 256x0e  BT=16, 8192 tiles, 2 WG/CU (128 weight VGPRs)
    eqlin<256, 1,   0,     0, 16, 2>
        <<<dim3(512), dim3(256), 0, stream>>>(x, w, out, 8192, 0.0625f);
    // block 1: 128x1o  BT=16, 8192 tiles, 3 WG/CU
    eqlin<128, 3, 256, 65536, 16, 3>
        <<<dim3(768), dim3(256), 0, stream>>>(x, w, out, 8192, 0.088388347648318447f);
    // block 2: 64x2e   BT=32, 4096 tiles, 3 WG/CU (LDS 46 KB)
    eqlin< 64, 5, 640, 81920, 32, 3>
        <<<dim3(768), dim3(256), 0, stream>>>(x, w, out, 4096, 0.125f);
    // block 3: 32x3o   BT=32, 4096 tiles, 4 WG/CU
    eqlin< 32, 7, 960, 86016, 32, 4>
        <<<dim3(1024), dim3(256), 0, stream>>>(x, w, out, 4096, 0.17677669529663689f);
}